// Round 20
// baseline (318.558 us; speedup 1.0000x reference)
//
#include <hip/hip_runtime.h>

typedef __attribute__((ext_vector_type(8))) short short8;
typedef __attribute__((ext_vector_type(4))) float f32x4;
typedef __attribute__((ext_vector_type(16))) float f32x16;
typedef unsigned short u16;

#define NTOK 49
#define NBLK 4096
#define LOG2E 1.4426950408889634f

// LDS pool (u16 units), 128 KB
#define XF  0       // x frags [tt2][ks16][64][8] (32x32 B-frags); later y frags [it4][h8][64][8]
#define QKP 16384   // per head 4096 u16: q[4][64][8] | k[4][64][8]   (16x16 layout, unchanged)
#define VTF 49152   // 32 slots x 512 u16: v^T frag f of head h at slot f*8+h (unchanged)
#define POOLN 65536 // 131072 B

// workspace byte offsets
#define WS_WQT 0          // u16 wqTf32[24][16][64][8]  = 393216  (32-col tiles; q part x SCQ)
#define WS_WOT 393216     // u16 woTf[16][8][64][8]     = 131072  (unchanged 16x16)
#define WS_BQS 524288     // float bqs[768] (q part x SCQ), pad to 4096
#define WS_BIAS 528384    // float biasf[8][16][64][4]  = 131072   (x LOG2E)
#define WS_MKG 659456     // float mkg[64][16][64][4]   = 1048576  (x LOG2E)
#define WS_CMB 1708032    // float cmb[64][8][16][64][4] = 8388608 (biasf+mkg)
#define WS_NEED (WS_CMB + 8388608)

__device__ __forceinline__ u16 f2bf(float f) {
  unsigned u = __float_as_uint(f);
  return (u16)((u + 0x7fffu + ((u >> 16) & 1u)) >> 16);
}
// single-instruction packed f32x2 -> bf16x2 (RNE)
__device__ __forceinline__ unsigned packbf(float a, float b) {
  unsigned r;
  asm("v_cvt_pk_bf16_f32 %0, %1, %2" : "=v"(r) : "v"(a), "v"(b));
  return r;
}

// Cross-lane fragment assembly (R7-verified; 5 clean passes).
__device__ __forceinline__ short8 asm_frag(unsigned c0p0, unsigned c0p1,
                                           unsigned c1p0, unsigned c1p1,
                                           int srcA, int srcB, bool cSel) {
  unsigned a0 = (unsigned)__shfl((int)c0p0, srcA);
  unsigned b0 = (unsigned)__shfl((int)c1p0, srcA);
  unsigned a1 = (unsigned)__shfl((int)c0p1, srcA);
  unsigned b1 = (unsigned)__shfl((int)c1p1, srcA);
  unsigned a2 = (unsigned)__shfl((int)c0p0, srcB);
  unsigned b2 = (unsigned)__shfl((int)c1p0, srcB);
  unsigned a3 = (unsigned)__shfl((int)c0p1, srcB);
  unsigned b3 = (unsigned)__shfl((int)c1p1, srcB);
  union { unsigned u[4]; short8 s8; } r;
  r.u[0] = cSel ? b0 : a0;
  r.u[1] = cSel ? b1 : a1;
  r.u[2] = cSel ? b2 : a2;
  r.u[3] = cSel ? b3 : a3;
  return r.s8;
}

// ---------------- prep1: 32-tile q/k/v weight frags, 16x16 wo frags, tables ----------------
__global__ void prep_kernel(const float* __restrict__ w_qkv,
                            const float* __restrict__ w_out,
                            const float* __restrict__ rel,
                            const float* __restrict__ mask,
                            const float* __restrict__ b_qkv,
                            u16* __restrict__ wqTf,
                            u16* __restrict__ woTf,
                            float* __restrict__ bqs,
                            float* __restrict__ biasf,
                            float* __restrict__ mkg) {
  const float SCQ = 0.17677669529663687f * LOG2E;
  const int stride = gridDim.x * blockDim.x;
  const int gid = blockIdx.x * blockDim.x + threadIdx.x;
  // wqTf32[ctg32][ks16][lane][e] = w_qkv[ks*16+(lane>>5)*8+e][ctg32*32+(lane&31)]
  for (int e = gid; e < 24 * 16 * 64 * 8; e += stride) {
    int eL = e & 7, ln = (e >> 3) & 63, ks = (e >> 9) & 15, ctg = e >> 13;
    int k = ks * 16 + (ln >> 5) * 8 + eL;
    int c = ctg * 32 + (ln & 31);
    float wv = w_qkv[k * 768 + c];
    if (c < 256) wv *= SCQ;               // fold softmax scale into q-projection
    wqTf[e] = f2bf(wv);
  }
  for (int e = gid; e < 16 * 8 * 64 * 8; e += stride) {
    int eL = e & 7, ln = (e >> 3) & 63, ks = (e >> 9) & 7, ctg = e >> 12;
    int k = ks * 32 + (ln >> 4) * 8 + eL;
    int c = ctg * 16 + (ln & 15);
    woTf[e] = f2bf(w_out[k * 256 + c]);
  }
  for (int e = gid; e < 768; e += stride)
    bqs[e] = b_qkv[e] * (e < 256 ? SCQ : 1.f);
  for (int e = gid; e < 8 * 16 * 64 * 4; e += stride) {
    int rg = e & 3, ln = (e >> 2) & 63, t = (e >> 8) & 15, hh = e >> 12;
    int i = (t >> 2) * 16 + (ln & 15);
    int j = (t & 3) * 16 + (ln >> 4) * 4 + rg;
    float v;
    if (j >= NTOK) v = -1e30f;
    else if (i >= NTOK) v = 0.f;
    else {
      int dh = i / 7 - j / 7 + 6;
      int dw = i % 7 - j % 7 + 6;
      v = rel[(dh * 13 + dw) * 8 + hh];
    }
    biasf[e] = v * LOG2E;
  }
  for (int e = gid; e < 64 * 16 * 64 * 4; e += stride) {
    int rg = e & 3, ln = (e >> 2) & 63, t = (e >> 8) & 15, wdw = e >> 12;
    int i = (t >> 2) * 16 + (ln & 15);
    int j = (t & 3) * 16 + (ln >> 4) * 4 + rg;
    mkg[e] = (i < NTOK && j < NTOK) ? mask[wdw * (NTOK * NTOK) + i * NTOK + j] * LOG2E : 0.f;
  }
}

// ---------------- prep2: cmb = biasf + mkg (R14-verified) ----------------
__global__ void prep2_kernel(const float* __restrict__ biasf,
                             const float* __restrict__ mkg,
                             float* __restrict__ cmb) {
  const int stride = gridDim.x * blockDim.x;
  for (int e = blockIdx.x * blockDim.x + threadIdx.x; e < 64 * 8 * 4096; e += stride) {
    int x = e & 4095, hh = (e >> 12) & 7, wdw = e >> 15;
    cmb[e] = biasf[hh * 4096 + x] + mkg[wdw * 4096 + x];
  }
}

// ---------------- fused window attention: 16 waves; ph1 on 32x32x16 MFMA ----------------
__global__ void __launch_bounds__(1024, 4) winattn_mfma(
    const float* __restrict__ x,
    const float* __restrict__ bqs,
    const float* __restrict__ b_out,
    const u16* __restrict__ wqTf,
    const u16* __restrict__ woTf,
    const float* __restrict__ biasf,
    const float* __restrict__ mkg,
    const float* __restrict__ cmb,   // may be nullptr -> fallback
    float* __restrict__ out)
{
  __shared__ u16 pool[POOLN];
  const int b = blockIdx.x, tid = threadIdx.x;
  const int lane = tid & 63, lo = lane & 15, hi = lane >> 4;
  const int w = tid >> 6;            // 0..15
  const int h = w & 7;               // head (attention phases)
  const int it0 = (w >> 3) * 2;      // i-tile half: 0 or 2
  const f32x4 zf = {0.f, 0.f, 0.f, 0.f};

  // ---- stage: x -> 32x32 B-frag order  [tt][ks16][lane][e]:
  //      element x[tt*32+(lane&31)][ks*16+(lane>>5)*8+e] ----
  {
    const float4* xg = (const float4*)(x + (size_t)b * (NTOK * 256));
    for (int e = tid; e < 49 * 64; e += 1024) {
      float4 v = xg[e];
      int r = e >> 6, c4 = (e & 63) << 2;
      int tt = r >> 5, ln = (r & 31) + 32 * ((c4 >> 3) & 1), ks = c4 >> 4;
      int addr = ((tt * 16 + ks) * 64 + ln) * 8 + (c4 & 7);
      *(uint2*)&pool[XF + addr] = make_uint2(packbf(v.x, v.y), packbf(v.z, v.w));
    }
    if (tid < 15 * 64) {   // zero-pad tokens 49..63
      int e = tid;
      int r = 49 + (e >> 6), c4 = (e & 63) << 2;
      int tt = r >> 5, ln = (r & 31) + 32 * ((c4 >> 3) & 1), ks = c4 >> 4;
      int addr = ((tt * 16 + ks) * 64 + ln) * 8 + (c4 & 7);
      *(uint2*)&pool[XF + addr] = make_uint2(0u, 0u);
    }
  }
  __syncthreads();   // (a) xf ready

  // ---- phase 1 (32x32x16): wave w -> token-tile tt=w>>3, col-slices hq=w&7 of q,k,v ----
  {
    const int hq = w & 7, tt = w >> 3;
    const int ls = hi >> 1;   // lane>>5
    f32x16 accq = {0.f,0.f,0.f,0.f,0.f,0.f,0.f,0.f,0.f,0.f,0.f,0.f,0.f,0.f,0.f,0.f};
    f32x16 acck = accq, accv = accq;
    #pragma unroll
    for (int ks = 0; ks < 16; ++ks) {
      short8 bx = *(const short8*)&pool[XF + ((tt * 16 + ks) * 64 + lane) * 8];
      short8 wq = *(const short8*)&wqTf[((size_t)((0  + hq) * 16 + ks) * 64 + lane) * 8];
      short8 wk = *(const short8*)&wqTf[((size_t)((8  + hq) * 16 + ks) * 64 + lane) * 8];
      short8 wv = *(const short8*)&wqTf[((size_t)((16 + hq) * 16 + ks) * 64 + lane) * 8];
      accq = __builtin_amdgcn_mfma_f32_32x32x16_bf16(wq, bx, accq, 0, 0, 0);
      acck = __builtin_amdgcn_mfma_f32_32x32x16_bf16(wk, bx, acck, 0, 0, 0);
      accv = __builtin_amdgcn_mfma_f32_32x32x16_bf16(bx, wv, accv, 0, 0, 0);
    }
    // q/k epilogue: D lane&31 = token within tt, regs: d = 8*q2 + 4*ls + r3 (channel in head hq)
    // -> 16x16 consumer layout: unit = head*4096 [+2048 for k] + ((t>>4)*64 + (t&15) + 16*q2)*8 + 4*ls
    {
      const int t = tt * 32 + (lane & 31);
      const int ubase = ((t >> 4) * 64 + (t & 15)) * 8 + 4 * ls;
      #pragma unroll
      for (int q2 = 0; q2 < 4; ++q2) {
        f32x4 bq4 = *(const f32x4*)(bqs + hq * 32 + q2 * 8 + ls * 4);
        f32x4 bk4 = *(const f32x4*)(bqs + 256 + hq * 32 + q2 * 8 + ls * 4);
        float q0 = accq[4*q2+0] + bq4[0], q1 = accq[4*q2+1] + bq4[1];
        float q2v = accq[4*q2+2] + bq4[2], q3 = accq[4*q2+3] + bq4[3];
        float k0 = acck[4*q2+0] + bk4[0], k1 = acck[4*q2+1] + bk4[1];
        float k2v = acck[4*q2+2] + bk4[2], k3 = acck[4*q2+3] + bk4[3];
        *(uint2*)&pool[QKP + hq * 4096 + ubase + 16 * q2 * 8] =
            make_uint2(packbf(q0, q1), packbf(q2v, q3));
        *(uint2*)&pool[QKP + hq * 4096 + 2048 + ubase + 16 * q2 * 8] =
            make_uint2(packbf(k0, k1), packbf(k2v, k3));
      }
    }
    // v epilogue (swapped: lane&31 = channel d, regs: token t = tt*32 + 8*q2+4*ls+r3)
    // -> v^T slot = ((d>>4)*2 + tt)*8 + hq; unit = slot*512 + ((d&15) + 16*q2)*8 + 4*ls
    {
      const int dv = lane & 31;
      const float bv = bqs[512 + hq * 32 + dv];
      const int slot = ((dv >> 4) * 2 + tt) * 8 + hq;
      const int vbase = slot * 512 + (dv & 15) * 8 + 4 * ls;
      #pragma unroll
      for (int q2 = 0; q2 < 4; ++q2) {
        float v0 = accv[4*q2+0] + bv, v1 = accv[4*q2+1] + bv;
        float v2 = accv[4*q2+2] + bv, v3 = accv[4*q2+3] + bv;
        *(uint2*)&pool[VTF + vbase + 16 * q2 * 8] =
            make_uint2(packbf(v0, v1), packbf(v2, v3));
      }
    }
  }
  __syncthreads();   // (b) q/k/v visible; XF dead (y may overwrite)

  // ---- phase 2+3: S^T tiles (it0..it0+1) + softmax; s pre-scaled via weights ----
  float rs0 = 0.f, rs1 = 0.f;
  unsigned pkp[4][2][2];
  {
    short8 ka0 = *(const short8*)&pool[QKP + h * 4096 + 2048 + ((it0 + 0) * 64 + lane) * 8];
    short8 ka1 = *(const short8*)&pool[QKP + h * 4096 + 2048 + ((it0 + 1) * 64 + lane) * 8];
    const float* cb;
    const float* mb = nullptr;
    if (cmb) {
      cb = cmb + (((size_t)(b & 63) * 8 + h) << 12);
    } else {
      cb = biasf + h * 4096;
      mb = mkg + (size_t)(b & 63) * 4096;
    }
    #pragma unroll
    for (int jt = 0; jt < 4; ++jt) {
      short8 qa = *(const short8*)&pool[QKP + h * 4096 + (jt * 64 + lane) * 8];
      f32x4 s0 = __builtin_amdgcn_mfma_f32_16x16x32_bf16(qa, ka0, zf, 0, 0, 0);
      f32x4 s1 = __builtin_amdgcn_mfma_f32_16x16x32_bf16(qa, ka1, zf, 0, 0, 0);
      {
        const int t = (it0 + 0) * 4 + jt;
        f32x4 c4 = *(const f32x4*)&cb[(t * 64 + lane) * 4];
        if (mb) {
          f32x4 m4 = *(const f32x4*)&mb[(t * 64 + lane) * 4];
          c4[0] += m4[0]; c4[1] += m4[1]; c4[2] += m4[2]; c4[3] += m4[3];
        }
        float p0 = exp2f(s0[0] + c4[0]);
        float p1 = exp2f(s0[1] + c4[1]);
        float p2 = exp2f(s0[2] + c4[2]);
        float p3 = exp2f(s0[3] + c4[3]);
        rs0 += (p0 + p1) + (p2 + p3);
        pkp[jt][0][0] = packbf(p0, p1);
        pkp[jt][0][1] = packbf(p2, p3);
      }
      {
        const int t = (it0 + 1) * 4 + jt;
        f32x4 c4 = *(const f32x4*)&cb[(t * 64 + lane) * 4];
        if (mb) {
          f32x4 m4 = *(const f32x4*)&mb[(t * 64 + lane) * 4];
          c4[0] += m4[0]; c4[1] += m4[1]; c4[2] += m4[2]; c4[3] += m4[3];
        }
        float p0 = exp2f(s1[0] + c4[0]);
        float p1 = exp2f(s1[1] + c4[1]);
        float p2 = exp2f(s1[2] + c4[2]);
        float p3 = exp2f(s1[3] + c4[3]);
        rs1 += (p0 + p1) + (p2 + p3);
        pkp[jt][1][0] = packbf(p0, p1);
        pkp[jt][1][1] = packbf(p2, p3);
      }
    }
  }
  float inv0, inv1;
  {
    float r2 = rs0 + __shfl_xor(rs0, 16);
    inv0 = 1.f / (r2 + __shfl_xor(r2, 32));
    float r3 = rs1 + __shfl_xor(rs1, 16);
    inv1 = 1.f / (r3 + __shfl_xor(r3, 32));
  }

  // ---- phase 4: PV; pb via shfl (asm_frag); y frags -> XF ----
  {
    const int srcA = lo + 32 * (hi & 1);
    const int srcB = srcA + 16;
    const bool cSel = (hi & 2) != 0;
    short8 va[2][2];
    #pragma unroll
    for (int dblk = 0; dblk < 2; ++dblk)
      #pragma unroll
      for (int k2 = 0; k2 < 2; ++k2)
        va[dblk][k2] = *(const short8*)&pool[VTF + ((dblk * 2 + k2) * 8 + h) * 512 + lane * 8];
    f32x4 ya[2][2];
    ya[0][0] = zf; ya[0][1] = zf; ya[1][0] = zf; ya[1][1] = zf;
    #pragma unroll
    for (int itL = 0; itL < 2; ++itL)
      #pragma unroll
      for (int k2 = 0; k2 < 2; ++k2) {
        short8 pb = asm_frag(pkp[2 * k2][itL][0], pkp[2 * k2][itL][1],
                             pkp[2 * k2 + 1][itL][0], pkp[2 * k2 + 1][itL][1], srcA, srcB, cSel);
        ya[0][itL] = __builtin_amdgcn_mfma_f32_16x16x32_bf16(va[0][k2], pb, ya[0][itL], 0, 0, 0);
        ya[1][itL] = __builtin_amdgcn_mfma_f32_16x16x32_bf16(va[1][k2], pb, ya[1][itL], 0, 0, 0);
      }
    #pragma unroll
    for (int itL = 0; itL < 2; ++itL) {
      const float iv = itL ? inv1 : inv0;
      #pragma unroll
      for (int dblk = 0; dblk < 2; ++dblk) {
        f32x4 yy = ya[dblk][itL];
        int hi2 = dblk * 2 + (hi >> 1);
        int eb = (hi & 1) * 4;
        *(uint2*)&pool[XF + (((it0 + itL) * 8 + h) * 64 + hi2 * 16 + lo) * 8 + eb] =
            make_uint2(packbf(yy[0] * iv, yy[1] * iv), packbf(yy[2] * iv, yy[3] * iv));
      }
    }
  }
  __syncthreads();   // (c) y frags ready

  // ---- phase 5: output projection (16x16, unchanged), 1 ctg per wave ----
  {
    f32x4 pacc[4];
    pacc[0] = zf; pacc[1] = zf; pacc[2] = zf; pacc[3] = zf;
    #pragma unroll
    for (int ks = 0; ks < 8; ++ks) {
      short8 wf = *(const short8*)&woTf[((size_t)(w * 8 + ks) * 64 + lane) * 8];
      #pragma unroll
      for (int rt = 0; rt < 4; ++rt) {
        short8 yb = *(const short8*)&pool[XF + ((rt * 8 + ks) * 64 + lane) * 8];
        pacc[rt] = __builtin_amdgcn_mfma_f32_16x16x32_bf16(wf, yb, pacc[rt], 0, 0, 0);
      }
    }
    float* og = out + (size_t)b * (NTOK * 256);
    const int cb2 = w * 16 + hi * 4;
    f32x4 bb = *(const f32x4*)(b_out + cb2);
    #pragma unroll
    for (int rt = 0; rt < 4; ++rt) {
      const int r = rt * 16 + lo;
      if (r < NTOK) {
        f32x4 vv = pacc[rt] + bb;
        *(f32x4*)(og + (size_t)r * 256 + cb2) = vv;
      }
    }
  }
}

extern "C" void kernel_launch(void* const* d_in, const int* in_sizes, int n_in,
                              void* d_out, int out_size, void* d_ws, size_t ws_size,
                              hipStream_t stream) {
  const float *x = nullptr, *mask = nullptr, *w_qkv = nullptr, *b_qkv = nullptr,
              *rel_t = nullptr, *w_out = nullptr, *b_out = nullptr;
  for (int i = 0; i < n_in; ++i) {
    const float* p = (const float*)d_in[i];
    switch (in_sizes[i]) {
      case 4096 * 49 * 256: x = p; break;
      case 64 * 49 * 49:    mask = p; break;
      case 256 * 768:       w_qkv = p; break;
      case 768:             b_qkv = p; break;
      case 169 * 8:         rel_t = p; break;
      case 256 * 256:       w_out = p; break;
      case 256:             b_out = p; break;
    }
  }
  char* wsb = (char*)d_ws;
  u16* wqTf    = (u16*)(wsb + WS_WQT);
  u16* woTf    = (u16*)(wsb + WS_WOT);
  float* bqs   = (float*)(wsb + WS_BQS);
  float* biasf = (float*)(wsb + WS_BIAS);
  float* mkg   = (float*)(wsb + WS_MKG);
  const bool fits = (ws_size >= (size_t)WS_NEED);
  float* cmb   = fits ? (float*)(wsb + WS_CMB) : nullptr;

  hipLaunchKernelGGL(prep_kernel, dim3(1024), dim3(256), 0, stream,
                     w_qkv, w_out, rel_t, mask, b_qkv, wqTf, woTf, bqs, biasf, mkg);
  if (fits) {
    hipLaunchKernelGGL(prep2_kernel, dim3(2048), dim3(256), 0, stream,
                       biasf, mkg, cmb);
  }
  hipLaunchKernelGGL(winattn_mfma, dim3(NBLK), dim3(1024), 0, stream,
                     x, bqs, b_out, wqTf, woTf, biasf, mkg, cmb, (float*)d_out);
}

// Round 21
// 281.866 us; speedup vs baseline: 1.1302x; 1.1302x over previous
//
#include <hip/hip_runtime.h>

typedef __attribute__((ext_vector_type(8))) short short8;
typedef __attribute__((ext_vector_type(4))) float f32x4;
typedef unsigned short u16;

#define NTOK 49
#define NBLK 4096
#define LOG2E 1.4426950408889634f

// LDS pool (u16 units), 128 KB
#define XF  0       // x frags [rt4][ks8][64][8] linear; later y frags [it4][h8][64][8]
#define QKP 16384   // per head 4096 u16: q[4][64][8] | k[4][64][8]
#define VTF 49152   // 32 slots x 512 u16: v^T frag f of head h at slot f*8+h
#define POOLN 65536 // 131072 B

// workspace byte offsets
#define WS_WQT 0          // u16 wqTf[48][8][64][8]    = 393216  (q ctgs pre-scaled by SCQ)
#define WS_WOT 393216     // u16 woTf[16][8][64][8]    = 131072
#define WS_BQS 524288     // float bqs[768] (q part x SCQ), pad to 4096
#define WS_BIAS 528384    // float biasf[8][16][64][4] = 131072   (x LOG2E)
#define WS_MKG 659456     // float mkg[64][16][64][4]  = 1048576  (x LOG2E)
#define WS_CMB 1708032    // float cmb[64][8][16][64][4] = 8388608 (biasf+mkg)
#define WS_NEED (WS_CMB + 8388608)

__device__ __forceinline__ u16 f2bf(float f) {
  unsigned u = __float_as_uint(f);
  return (u16)((u + 0x7fffu + ((u >> 16) & 1u)) >> 16);
}
// single-instruction packed f32x2 -> bf16x2 (RNE)
__device__ __forceinline__ unsigned packbf(float a, float b) {
  unsigned r;
  asm("v_cvt_pk_bf16_f32 %0, %1, %2" : "=v"(r) : "v"(a), "v"(b));
  return r;
}

// Cross-lane fragment assembly (R7-verified; 5 clean passes R7/R10/R11/R14/R19).
__device__ __forceinline__ short8 asm_frag(unsigned c0p0, unsigned c0p1,
                                           unsigned c1p0, unsigned c1p1,
                                           int srcA, int srcB, bool cSel) {
  unsigned a0 = (unsigned)__shfl((int)c0p0, srcA);
  unsigned b0 = (unsigned)__shfl((int)c1p0, srcA);
  unsigned a1 = (unsigned)__shfl((int)c0p1, srcA);
  unsigned b1 = (unsigned)__shfl((int)c1p1, srcA);
  unsigned a2 = (unsigned)__shfl((int)c0p0, srcB);
  unsigned b2 = (unsigned)__shfl((int)c1p0, srcB);
  unsigned a3 = (unsigned)__shfl((int)c0p1, srcB);
  unsigned b3 = (unsigned)__shfl((int)c1p1, srcB);
  union { unsigned u[4]; short8 s8; } r;
  r.u[0] = cSel ? b0 : a0;
  r.u[1] = cSel ? b1 : a1;
  r.u[2] = cSel ? b2 : a2;
  r.u[3] = cSel ? b3 : a3;
  return r.s8;
}

// ---------------- prep1: frag-order weights (q x SCQ), scaled bias/mask tables, bqs ----------------
__global__ void prep_kernel(const float* __restrict__ w_qkv,
                            const float* __restrict__ w_out,
                            const float* __restrict__ rel,
                            const float* __restrict__ mask,
                            const float* __restrict__ b_qkv,
                            u16* __restrict__ wqTf,
                            u16* __restrict__ woTf,
                            float* __restrict__ bqs,
                            float* __restrict__ biasf,
                            float* __restrict__ mkg) {
  const float SCQ = 0.17677669529663687f * LOG2E;
  const int stride = gridDim.x * blockDim.x;
  const int gid = blockIdx.x * blockDim.x + threadIdx.x;
  for (int e = gid; e < 48 * 8 * 64 * 8; e += stride) {
    int eL = e & 7, ln = (e >> 3) & 63, ks = (e >> 9) & 7, ctg = e >> 12;
    int k = ks * 32 + (ln >> 4) * 8 + eL;
    int c = ctg * 16 + (ln & 15);
    float wv = w_qkv[k * 768 + c];
    if (ctg < 16) wv *= SCQ;               // fold softmax scale into q-projection
    wqTf[e] = f2bf(wv);
  }
  for (int e = gid; e < 16 * 8 * 64 * 8; e += stride) {
    int eL = e & 7, ln = (e >> 3) & 63, ks = (e >> 9) & 7, ctg = e >> 12;
    int k = ks * 32 + (ln >> 4) * 8 + eL;
    int c = ctg * 16 + (ln & 15);
    woTf[e] = f2bf(w_out[k * 256 + c]);
  }
  for (int e = gid; e < 768; e += stride)
    bqs[e] = b_qkv[e] * (e < 256 ? SCQ : 1.f);
  for (int e = gid; e < 8 * 16 * 64 * 4; e += stride) {
    int rg = e & 3, ln = (e >> 2) & 63, t = (e >> 8) & 15, hh = e >> 12;
    int i = (t >> 2) * 16 + (ln & 15);
    int j = (t & 3) * 16 + (ln >> 4) * 4 + rg;
    float v;
    if (j >= NTOK) v = -1e30f;
    else if (i >= NTOK) v = 0.f;
    else {
      int dh = i / 7 - j / 7 + 6;
      int dw = i % 7 - j % 7 + 6;
      v = rel[(dh * 13 + dw) * 8 + hh];
    }
    biasf[e] = v * LOG2E;
  }
  for (int e = gid; e < 64 * 16 * 64 * 4; e += stride) {
    int rg = e & 3, ln = (e >> 2) & 63, t = (e >> 8) & 15, wdw = e >> 12;
    int i = (t >> 2) * 16 + (ln & 15);
    int j = (t & 3) * 16 + (ln >> 4) * 4 + rg;
    mkg[e] = (i < NTOK && j < NTOK) ? mask[wdw * (NTOK * NTOK) + i * NTOK + j] * LOG2E : 0.f;
  }
}

// ---------------- prep2: cmb[wdw][h][x] = biasf[h][x] + mkg[wdw][x] (pure stream) ----------------
__global__ void prep2_kernel(const float* __restrict__ biasf,
                             const float* __restrict__ mkg,
                             float* __restrict__ cmb) {
  const int stride = gridDim.x * blockDim.x;
  for (int e = blockIdx.x * blockDim.x + threadIdx.x; e < 64 * 8 * 4096; e += stride) {
    int x = e & 4095, hh = (e >> 12) & 7, wdw = e >> 15;
    cmb[e] = biasf[hh * 4096 + x] + mkg[wdw * 4096 + x];
  }
}

// ---------------- fused window attention: 16 waves (R14/R19 champion lineage) ----------------
__global__ void __launch_bounds__(1024, 4) winattn_mfma(
    const float* __restrict__ x,
    const float* __restrict__ bqs,
    const float* __restrict__ b_out,
    const u16* __restrict__ wqTf,
    const u16* __restrict__ woTf,
    const float* __restrict__ biasf,
    const float* __restrict__ mkg,
    const float* __restrict__ cmb,   // may be nullptr (ws too small) -> fallback
    float* __restrict__ out)
{
  __shared__ u16 pool[POOLN];
  const int b = blockIdx.x, tid = threadIdx.x;
  const int lane = tid & 63, lo = lane & 15, hi = lane >> 4;
  const int w = tid >> 6;            // 0..15
  const int h = w & 7;               // head (attention phases)
  const int it0 = (w >> 3) * 2;      // i-tile half: 0 or 2
  const f32x4 zf = {0.f, 0.f, 0.f, 0.f};

  // ---- stage: x -> linear frag order ----
  {
    const float4* xg = (const float4*)(x + (size_t)b * (NTOK * 256));
    for (int e = tid; e < 49 * 64; e += 1024) {
      float4 v = xg[e];
      int r = e >> 6, c4 = (e & 63) << 2;
      int addr = (((r >> 4) * 8 + (c4 >> 5)) * 64 + ((c4 >> 3) & 3) * 16 + (r & 15)) * 8 + (c4 & 7);
      *(uint2*)&pool[XF + addr] = make_uint2(packbf(v.x, v.y), packbf(v.z, v.w));
    }
    if (tid < 15 * 64) {   // zero-pad tokens 49..63
      int e = tid;
      int r = 49 + (e >> 6), c4 = (e & 63) << 2;
      int addr = (((r >> 4) * 8 + (c4 >> 5)) * 64 + ((c4 >> 3) & 3) * 16 + (r & 15)) * 8 + (c4 & 7);
      *(uint2*)&pool[XF + addr] = make_uint2(0u, 0u);
    }
  }
  __syncthreads();   // (a) xf ready

  // ---- phase 1: QKV GEMM. wave w: q/k ctgs {2w,2w+1}; v ctg 32+w swapped-operand ----
  {
    const int ctq0 = 2 * w, ctq1 = 2 * w + 1, ctv = 32 + w;
    f32x4 acc[3][4];
    #pragma unroll
    for (int ct = 0; ct < 3; ++ct)
      #pragma unroll
      for (int rt = 0; rt < 4; ++rt) acc[ct][rt] = zf;
    #pragma unroll
    for (int ks = 0; ks < 8; ++ks) {
      short8 bx[4];
      #pragma unroll
      for (int rt = 0; rt < 4; ++rt)
        bx[rt] = *(const short8*)&pool[XF + ((rt * 8 + ks) * 64 + lane) * 8];
      short8 af0 = *(const short8*)&wqTf[((size_t)(ctq0 * 8 + ks) * 64 + lane) * 8];
      short8 af1 = *(const short8*)&wqTf[((size_t)(ctq1 * 8 + ks) * 64 + lane) * 8];
      short8 afv = *(const short8*)&wqTf[((size_t)(ctv * 8 + ks) * 64 + lane) * 8];
      #pragma unroll
      for (int rt = 0; rt < 4; ++rt) {
        acc[0][rt] = __builtin_amdgcn_mfma_f32_16x16x32_bf16(af0, bx[rt], acc[0][rt], 0, 0, 0);
        acc[1][rt] = __builtin_amdgcn_mfma_f32_16x16x32_bf16(af1, bx[rt], acc[1][rt], 0, 0, 0);
        acc[2][rt] = __builtin_amdgcn_mfma_f32_16x16x32_bf16(bx[rt], afv, acc[2][rt], 0, 0, 0);
      }
    }
    // epilogue q/k: wave w<8 -> q[head w]; w>=8 -> k[head w-8]
    const int qkbase = QKP + (w & 7) * 4096 + ((w >= 8) ? 2048 : 0);
    #pragma unroll
    for (int ct = 0; ct < 2; ++ct) {
      const int ctg = 2 * w + ct;
      f32x4 bias = *(const f32x4*)(bqs + ctg * 16 + hi * 4);
      #pragma unroll
      for (int rt = 0; rt < 4; ++rt) {
        f32x4 v = acc[ct][rt] + bias;
        int hi2 = ct * 2 + (hi >> 1);
        int eb = (hi & 1) * 4;
        *(uint2*)&pool[qkbase + (rt * 64 + hi2 * 16 + lo) * 8 + eb] =
            make_uint2(packbf(v[0], v[1]), packbf(v[2], v[3]));
      }
    }
    // epilogue v (swapped D: lane lo = channel, regs = tokens) -> packed b64
    {
      const int vhead = w >> 1, dblk = w & 1;
      const float bv = bqs[ctv * 16 + lo];
      #pragma unroll
      for (int rt = 0; rt < 4; ++rt) {
        f32x4 v = acc[2][rt];
        float v0 = v[0] + bv, v1 = v[1] + bv, v2 = v[2] + bv, v3 = v[3] + bv;
        int f = dblk * 2 + (rt >> 1);
        int hiR = (rt & 1) * 2 + (hi >> 1);
        int eb = (hi & 1) * 4;
        *(uint2*)&pool[VTF + (f * 8 + vhead) * 512 + (hiR * 16 + lo) * 8 + eb] =
            make_uint2(packbf(v0, v1), packbf(v2, v3));
      }
    }
  }
  __syncthreads();   // (b) q/k/v visible; XF dead (y may overwrite)

  // ---- phase 2+3: S^T tiles (it0..it0+1) + softmax; s pre-scaled via weights ----
  float rs0 = 0.f, rs1 = 0.f;
  unsigned pkp[4][2][2];
  {
    short8 ka0 = *(const short8*)&pool[QKP + h * 4096 + 2048 + ((it0 + 0) * 64 + lane) * 8];
    short8 ka1 = *(const short8*)&pool[QKP + h * 4096 + 2048 + ((it0 + 1) * 64 + lane) * 8];
    const float* cb;
    const float* mb = nullptr;
    if (cmb) {
      cb = cmb + (((size_t)(b & 63) * 8 + h) << 12);
    } else {
      cb = biasf + h * 4096;
      mb = mkg + (size_t)(b & 63) * 4096;
    }
    #pragma unroll
    for (int jt = 0; jt < 4; ++jt) {
      short8 qa = *(const short8*)&pool[QKP + h * 4096 + (jt * 64 + lane) * 8];
      f32x4 s0 = __builtin_amdgcn_mfma_f32_16x16x32_bf16(qa, ka0, zf, 0, 0, 0);
      f32x4 s1 = __builtin_amdgcn_mfma_f32_16x16x32_bf16(qa, ka1, zf, 0, 0, 0);
      {
        const int t = (it0 + 0) * 4 + jt;
        f32x4 c4 = *(const f32x4*)&cb[(t * 64 + lane) * 4];
        if (mb) {
          f32x4 m4 = *(const f32x4*)&mb[(t * 64 + lane) * 4];
          c4[0] += m4[0]; c4[1] += m4[1]; c4[2] += m4[2]; c4[3] += m4[3];
        }
        float p0 = exp2f(s0[0] + c4[0]);
        float p1 = exp2f(s0[1] + c4[1]);
        float p2 = exp2f(s0[2] + c4[2]);
        float p3 = exp2f(s0[3] + c4[3]);
        rs0 += (p0 + p1) + (p2 + p3);
        pkp[jt][0][0] = packbf(p0, p1);
        pkp[jt][0][1] = packbf(p2, p3);
      }
      {
        const int t = (it0 + 1) * 4 + jt;
        f32x4 c4 = *(const f32x4*)&cb[(t * 64 + lane) * 4];
        if (mb) {
          f32x4 m4 = *(const f32x4*)&mb[(t * 64 + lane) * 4];
          c4[0] += m4[0]; c4[1] += m4[1]; c4[2] += m4[2]; c4[3] += m4[3];
        }
        float p0 = exp2f(s1[0] + c4[0]);
        float p1 = exp2f(s1[1] + c4[1]);
        float p2 = exp2f(s1[2] + c4[2]);
        float p3 = exp2f(s1[3] + c4[3]);
        rs1 += (p0 + p1) + (p2 + p3);
        pkp[jt][1][0] = packbf(p0, p1);
        pkp[jt][1][1] = packbf(p2, p3);
      }
    }
  }
  float inv0, inv1;
  {
    float r2 = rs0 + __shfl_xor(rs0, 16);
    inv0 = 1.f / (r2 + __shfl_xor(r2, 32));
    float r3 = rs1 + __shfl_xor(rs1, 16);
    inv1 = 1.f / (r3 + __shfl_xor(r3, 32));
  }

  // ---- phase 4: PV; pb via shfl (asm_frag); y frags -> XF ----
  {
    const int srcA = lo + 32 * (hi & 1);
    const int srcB = srcA + 16;
    const bool cSel = (hi & 2) != 0;
    short8 va[2][2];
    #pragma unroll
    for (int dblk = 0; dblk < 2; ++dblk)
      #pragma unroll
      for (int k2 = 0; k2 < 2; ++k2)
        va[dblk][k2] = *(const short8*)&pool[VTF + ((dblk * 2 + k2) * 8 + h) * 512 + lane * 8];
    f32x4 ya[2][2];
    ya[0][0] = zf; ya[0][1] = zf; ya[1][0] = zf; ya[1][1] = zf;
    #pragma unroll
    for (int itL = 0; itL < 2; ++itL)
      #pragma unroll
      for (int k2 = 0; k2 < 2; ++k2) {
        short8 pb = asm_frag(pkp[2 * k2][itL][0], pkp[2 * k2][itL][1],
                             pkp[2 * k2 + 1][itL][0], pkp[2 * k2 + 1][itL][1], srcA, srcB, cSel);
        ya[0][itL] = __builtin_amdgcn_mfma_f32_16x16x32_bf16(va[0][k2], pb, ya[0][itL], 0, 0, 0);
        ya[1][itL] = __builtin_amdgcn_mfma_f32_16x16x32_bf16(va[1][k2], pb, ya[1][itL], 0, 0, 0);
      }
    #pragma unroll
    for (int itL = 0; itL < 2; ++itL) {
      const float iv = itL ? inv1 : inv0;
      #pragma unroll
      for (int dblk = 0; dblk < 2; ++dblk) {
        f32x4 yy = ya[dblk][itL];
        int hi2 = dblk * 2 + (hi >> 1);
        int eb = (hi & 1) * 4;
        *(uint2*)&pool[XF + (((it0 + itL) * 8 + h) * 64 + hi2 * 16 + lo) * 8 + eb] =
            make_uint2(packbf(yy[0] * iv, yy[1] * iv), packbf(yy[2] * iv, yy[3] * iv));
      }
    }
  }
  __syncthreads();   // (c) y frags ready

  // ---- phase 5: output projection, 1 ctg per wave ----
  {
    f32x4 pacc[4];
    pacc[0] = zf; pacc[1] = zf; pacc[2] = zf; pacc[3] = zf;
    #pragma unroll
    for (int ks = 0; ks < 8; ++ks) {
      short8 wf = *(const short8*)&woTf[((size_t)(w * 8 + ks) * 64 + lane) * 8];
      #pragma unroll
      for (int rt = 0; rt < 4; ++rt) {
        short8 yb = *(const short8*)&pool[XF + ((rt * 8 + ks) * 64 + lane) * 8];
        pacc[rt] = __builtin_amdgcn_mfma_f32_16x16x32_bf16(wf, yb, pacc[rt], 0, 0, 0);
      }
    }
    float* og = out + (size_t)b * (NTOK * 256);
    const int cb2 = w * 16 + hi * 4;
    f32x4 bb = *(const f32x4*)(b_out + cb2);
    #pragma unroll
    for (int rt = 0; rt < 4; ++rt) {
      const int r = rt * 16 + lo;
      if (r < NTOK) {
        f32x4 vv = pacc[rt] + bb;
        *(f32x4*)(og + (size_t)r * 256 + cb2) = vv;
      }
    }
  }
}

extern "C" void kernel_launch(void* const* d_in, const int* in_sizes, int n_in,
                              void* d_out, int out_size, void* d_ws, size_t ws_size,
                              hipStream_t stream) {
  const float *x = nullptr, *mask = nullptr, *w_qkv = nullptr, *b_qkv = nullptr,
              *rel_t = nullptr, *w_out = nullptr, *b_out = nullptr;
  for (int i = 0; i < n_in; ++i) {
    const float* p = (const float*)d_in[i];
    switch (in_sizes[i]) {
      case 4096 * 49 * 256: x = p; break;
      case 64 * 49 * 49:    mask = p; break;
      case 256 * 768:       w_qkv = p; break;
      case 768:             b_qkv = p; break;
      case 169 * 8:         rel_t = p; break;
      case 256 * 256:       w_out = p; break;
      case 256:             b_out = p; break;
    }
  }
  char* wsb = (char*)d_ws;
  u16* wqTf    = (u16*)(wsb + WS_WQT);
  u16* woTf    = (u16*)(wsb + WS_WOT);
  float* bqs   = (float*)(wsb + WS_BQS);
  float* biasf = (float*)(wsb + WS_BIAS);
  float* mkg   = (float*)(wsb + WS_MKG);
  const bool fits = (ws_size >= (size_t)WS_NEED);
  float* cmb   = fits ? (float*)(wsb + WS_CMB) : nullptr;

  hipLaunchKernelGGL(prep_kernel, dim3(1024), dim3(256), 0, stream,
                     w_qkv, w_out, rel_t, mask, b_qkv, wqTf, woTf, bqs, biasf, mkg);
  if (fits) {
    hipLaunchKernelGGL(prep2_kernel, dim3(2048), dim3(256), 0, stream,
                       biasf, mkg, cmb);
  }
  hipLaunchKernelGGL(winattn_mfma, dim3(NBLK), dim3(1024), 0, stream,
                     x, bqs, b_out, wqTf, woTf, biasf, mkg, cmb, (float*)d_out);
}